// Round 3
// baseline (651.579 us; speedup 1.0000x reference)
//
#include <hip/hip_runtime.h>
#include <hip/hip_bf16.h>

typedef __bf16 bf16;
typedef bf16 bf16x8 __attribute__((ext_vector_type(8)));
typedef float f32x4 __attribute__((ext_vector_type(4)));

// ---------------------------------------------------------------------------
// fp32 -> bf16 elementwise convert (8 elems/thread, 32B in / 16B out per lane)
// ---------------------------------------------------------------------------
__global__ __launch_bounds__(256) void f32_to_bf16(const float* __restrict__ in,
                                                   bf16* __restrict__ out) {
  const size_t i = ((size_t)blockIdx.x * 256 + threadIdx.x) * 8;
  float4 a = *(const float4*)(in + i);
  float4 b = *(const float4*)(in + i + 4);
  bf16x8 o;
  o[0] = (bf16)a.x; o[1] = (bf16)a.y; o[2] = (bf16)a.z; o[3] = (bf16)a.w;
  o[4] = (bf16)b.x; o[5] = (bf16)b.y; o[6] = (bf16)b.z; o[7] = (bf16)b.w;
  *(bf16x8*)(out + i) = o;
}

// ---------------------------------------------------------------------------
// Transpose fp32 (R x C) -> bf16 (C x R), 32x32 LDS tiles
// ---------------------------------------------------------------------------
__global__ __launch_bounds__(256) void transpose_f32_bf16(const float* __restrict__ in,
                                                          bf16* __restrict__ out,
                                                          int R, int C) {
  __shared__ float tile[32][33];
  const int bx = blockIdx.x * 32;  // col base in input
  const int by = blockIdx.y * 32;  // row base in input
  const int tx = threadIdx.x & 31;
  const int ty = threadIdx.x >> 5;  // 0..7
#pragma unroll
  for (int i = 0; i < 4; i++) {
    int r = by + ty + i * 8;
    tile[ty + i * 8][tx] = in[(size_t)r * C + bx + tx];
  }
  __syncthreads();
#pragma unroll
  for (int i = 0; i < 4; i++) {
    int r = bx + ty + i * 8;  // row in output (= col in input)
    out[(size_t)r * R + by + tx] = (bf16)tile[tx][ty + i * 8];
  }
}

// ---------------------------------------------------------------------------
// GEMM: C[M,N] = A[M,K] * B[K,N], with B given transposed (BT[N,K]).
// bf16 in, OT out (bf16 or float), fp32 MFMA accumulate. 128x128 tile, BK=64.
// Explicit staging (vector load -> LDS store), m93 structure.
// Requires M%128==0, N%128==0, K%64==0.
// ---------------------------------------------------------------------------
template <typename OT>
__global__ __launch_bounds__(256) void gemm_bt(const bf16* __restrict__ A,
                                               const bf16* __restrict__ BT,
                                               OT* __restrict__ C,
                                               int M, int N, int K) {
  __shared__ __attribute__((aligned(16))) bf16 As[128 * 64];
  __shared__ __attribute__((aligned(16))) bf16 Bs[128 * 64];
  const int tid = threadIdx.x;
  const int lane = tid & 63;
  const int wave = tid >> 6;
  const int wm = wave & 1, wn = wave >> 1;
  const int m0 = blockIdx.y * 128, n0 = blockIdx.x * 128;

  f32x4 acc[4][4];
#pragma unroll
  for (int i = 0; i < 4; i++)
#pragma unroll
    for (int j = 0; j < 4; j++) acc[i][j] = f32x4{0.f, 0.f, 0.f, 0.f};

  for (int k0 = 0; k0 < K; k0 += 64) {
    // stage 128 rows x 64 cols: 1024 chunks of 8 bf16; 4 chunks/thread.
    bf16x8 av[4], bv[4];
#pragma unroll
    for (int i = 0; i < 4; i++) {
      int c = tid + 256 * i;
      int row = c >> 3, col = (c & 7) * 8;
      av[i] = *(const bf16x8*)(A + (size_t)(m0 + row) * K + k0 + col);
      bv[i] = *(const bf16x8*)(BT + (size_t)(n0 + row) * K + k0 + col);
    }
#pragma unroll
    for (int i = 0; i < 4; i++) {
      int c = tid + 256 * i;
      int row = c >> 3, col = (c & 7) * 8;
      *(bf16x8*)(As + row * 64 + col) = av[i];
      *(bf16x8*)(Bs + row * 64 + col) = bv[i];
    }
    __syncthreads();

    const int fr = lane & 15;
#pragma unroll
    for (int kk = 0; kk < 64; kk += 32) {
      const int kq = kk + ((lane >> 4) << 3);
      bf16x8 af[4], bfv[4];
#pragma unroll
      for (int mi = 0; mi < 4; mi++)
        af[mi] = *(const bf16x8*)(As + (wm * 64 + mi * 16 + fr) * 64 + kq);
#pragma unroll
      for (int ni = 0; ni < 4; ni++)
        bfv[ni] = *(const bf16x8*)(Bs + (wn * 64 + ni * 16 + fr) * 64 + kq);
#pragma unroll
      for (int mi = 0; mi < 4; mi++)
#pragma unroll
        for (int ni = 0; ni < 4; ni++)
          acc[mi][ni] = __builtin_amdgcn_mfma_f32_16x16x32_bf16(af[mi], bfv[ni], acc[mi][ni], 0, 0, 0);
    }
    __syncthreads();
  }

  // epilogue: D layout col = lane&15, row = (lane>>4)*4 + r  [m89/m91-verified]
  const int col0 = n0 + wn * 64 + (lane & 15);
  const int row00 = m0 + wm * 64 + ((lane >> 4) << 2);
#pragma unroll
  for (int mi = 0; mi < 4; mi++)
#pragma unroll
    for (int ni = 0; ni < 4; ni++)
#pragma unroll
      for (int r = 0; r < 4; r++) {
        int row = row00 + mi * 16 + r;
        int col = col0 + ni * 16;
        C[(size_t)row * N + col] = (OT)acc[mi][ni][r];
      }
}

// ---------------------------------------------------------------------------
// Linear attention phase 1: per (b,h) compute kv[64][64] = sum_t kf[t]⊗v[t]
// and ksum[64] = sum_t kf[t], kf = elu(rope(k)) + 1.
// grid (64 bh, 8 t-chunks), 256 threads. fp32 atomics into zeroed ws.
// ---------------------------------------------------------------------------
__global__ __launch_bounds__(256) void attn_kv(const bf16* __restrict__ qkv,
                                               float* __restrict__ kvg,
                                               float* __restrict__ ksumg) {
  const int bh = blockIdx.x;
  const int b = bh >> 4, h = bh & 15;
  const int t0 = blockIdx.y * 512;
  __shared__ float kbuf[4][64], vbuf[4][64], kfbuf[4][64];
  const int tid = threadIdx.x;
  const int d = tid & 63;
  const int g = tid >> 6;  // 0..3: staged row for load/kf; v-group for accum

  const int j = d & 31;
  const float invf = (float)exp(-((double)j / 32.0) * log(500000.0));

  float acc[16];
#pragma unroll
  for (int i = 0; i < 16; i++) acc[i] = 0.f;
  float ks = 0.f;

  for (int it = 0; it < 128; it++) {
    const int t = t0 + it * 4 + g;
    const bf16* base = qkv + (size_t)(b * 4096 + t) * 3072 + h * 64;
    kbuf[g][d] = (float)base[1024 + d];
    vbuf[g][d] = (float)base[2048 + d];
    __syncthreads();
    // rope + elu+1 on k
    {
      float x1 = kbuf[g][d];
      float x2 = kbuf[g][d ^ 32];
      float sn, cs;
      sincosf((float)t * invf, &sn, &cs);
      float z = (d < 32) ? (x1 * cs - x2 * sn) : (x1 * cs + x2 * sn);
      kfbuf[g][d] = z > 0.f ? z + 1.f : __expf(z);
    }
    __syncthreads();
    // accumulate: thread owns (d, v-group g)
    float kf0 = kfbuf[0][d], kf1 = kfbuf[1][d], kf2 = kfbuf[2][d], kf3 = kfbuf[3][d];
    ks += kf0 + kf1 + kf2 + kf3;
#pragma unroll
    for (int i = 0; i < 16; i++) {
      int vv = g * 16 + i;
      acc[i] += kf0 * vbuf[0][vv] + kf1 * vbuf[1][vv] + kf2 * vbuf[2][vv] + kf3 * vbuf[3][vv];
    }
    __syncthreads();
  }
#pragma unroll
  for (int i = 0; i < 16; i++)
    atomicAdd(&kvg[(size_t)bh * 4096 + d * 64 + g * 16 + i], acc[i]);
  if (g == 0) atomicAdd(&ksumg[bh * 64 + d], ks);
}

// ---------------------------------------------------------------------------
// Linear attention phase 2: out[t] = (qf[t] @ kv) / max(qf[t]·ksum, 1e-6)
// grid (64 t-chunks, 64 bh), 256 threads.
// ---------------------------------------------------------------------------
__global__ __launch_bounds__(256) void attn_out(const bf16* __restrict__ qkv,
                                                const float* __restrict__ kvg,
                                                const float* __restrict__ ksumg,
                                                bf16* __restrict__ attn) {
  const int bh = blockIdx.y;
  const int b = bh >> 4, h = bh & 15;
  const int t0 = blockIdx.x * 64;
  __shared__ float qf[64][65];
  __shared__ float kvs[64][64];
  __shared__ float ksums[64];
  const int tid = threadIdx.x;

  // stage raw q
#pragma unroll
  for (int j = 0; j < 16; j++) {
    int idx = tid + 256 * j;
    int tl = idx >> 6, d = idx & 63;
    qf[tl][d] = (float)qkv[(size_t)(b * 4096 + t0 + tl) * 3072 + h * 64 + d];
  }
  // stage kv + ksum
#pragma unroll
  for (int j = 0; j < 16; j++) {
    int idx = tid + 256 * j;
    kvs[idx >> 6][idx & 63] = kvg[(size_t)bh * 4096 + idx];
  }
  if (tid < 64) ksums[tid] = ksumg[bh * 64 + tid];
  __syncthreads();

  // rope + scale + elu+1 in place (each thread owns both halves of its pairs)
  {
    const int pd = tid & 31;
    const float invf = (float)exp(-((double)pd / 32.0) * log(500000.0));
#pragma unroll
    for (int j = 0; j < 8; j++) {
      int idx = tid + 256 * j;       // 0..2047
      int tl = idx >> 5;             // 0..63
      int d = idx & 31;              // == pd (256 multiple of 32)
      float x1 = qf[tl][d], x2 = qf[tl][d + 32];
      float sn, cs;
      sincosf((float)(t0 + tl) * invf, &sn, &cs);
      float r1 = (x1 * cs - x2 * sn) * 0.125f;
      float r2 = (x2 * cs + x1 * sn) * 0.125f;
      qf[tl][d] = r1 > 0.f ? r1 + 1.f : __expf(r1);
      qf[tl][d + 32] = r2 > 0.f ? r2 + 1.f : __expf(r2);
    }
  }
  __syncthreads();

  const int tl = tid >> 2, s = tid & 3;
  float dn = 0.f;
#pragma unroll
  for (int d2 = 0; d2 < 64; d2++) dn += qf[tl][d2] * ksums[d2];
  dn = fmaxf(dn, 1e-6f);
  const float rdn = 1.f / dn;

  float acc[16];
#pragma unroll
  for (int i = 0; i < 16; i++) acc[i] = 0.f;
  for (int d2 = 0; d2 < 64; d2++) {
    float qv = qf[tl][d2];
#pragma unroll
    for (int i = 0; i < 16; i++) acc[i] += qv * kvs[d2][s * 16 + i];
  }

  union {
    __bf16 hh[16];
    uint4 qq[2];
  } ob;
#pragma unroll
  for (int i = 0; i < 16; i++) ob.hh[i] = (__bf16)(acc[i] * rdn);
  bf16* dst = attn + (size_t)(b * 4096 + t0 + tl) * 1024 + h * 64 + s * 16;
  *reinterpret_cast<uint4*>(dst) = ob.qq[0];
  *reinterpret_cast<uint4*>(dst + 8) = ob.qq[1];
}

// ---------------------------------------------------------------------------
// Workspace layout (bytes):
//   kvg   f32  [64*64*64]   @ 0          size   1048576
//   ksumg f32  [64*64]      @ 1048576    size     16384
//   WqkvT bf16 [3072,1024]  @ 1064960    size   6291456
//   WoutT bf16 [1024,1024]  @ 7356416    size   2097152
//   attn  bf16 [16384,1024] @ 9453568    size  33554432
//   qkvB  bf16 [16384,3072] @ 43008000   size 100663296
//   xB    bf16 [16384,1024] @ 143671296  size  33554432
//   total 177225728 (~169 MiB)
// ---------------------------------------------------------------------------
extern "C" void kernel_launch(void* const* d_in, const int* in_sizes, int n_in,
                              void* d_out, int out_size, void* d_ws, size_t ws_size,
                              hipStream_t stream) {
  if (ws_size < 177225728ULL) return;  // signature: finite absmax == max|ref| ~5.88e-2

  const float* x = (const float*)d_in[0];      // fp32 per reference dtype
  const float* Wqkv = (const float*)d_in[1];
  const float* Wout = (const float*)d_in[2];
  float* out = (float*)d_out;                  // fp32 output per reference
  char* ws = (char*)d_ws;

  float* kvg = (float*)(ws);
  float* ksumg = (float*)(ws + 1048576);
  bf16* WqkvT = (bf16*)(ws + 1064960);
  bf16* WoutT = (bf16*)(ws + 7356416);
  bf16* attn = (bf16*)(ws + 9453568);
  bf16* qkvB = (bf16*)(ws + 43008000);
  bf16* xB = (bf16*)(ws + 143671296);

  // ws is re-poisoned 0xAA before every launch: zero the accumulators.
  hipMemsetAsync(ws, 0, 1048576 + 16384, stream);

  // input conversions: x -> bf16; W -> transposed bf16 (BT layout for GEMM)
  f32_to_bf16<<<16777216 / (256 * 8), 256, 0, stream>>>(x, xB);
  transpose_f32_bf16<<<dim3(3072 / 32, 1024 / 32), 256, 0, stream>>>(Wqkv, WqkvT, 1024, 3072);
  transpose_f32_bf16<<<dim3(1024 / 32, 1024 / 32), 256, 0, stream>>>(Wout, WoutT, 1024, 1024);

  // qkv = x @ W_qkv : M=16384, N=3072, K=1024   (bf16 out)
  gemm_bt<bf16><<<dim3(3072 / 128, 16384 / 128), 256, 0, stream>>>(xB, WqkvT, qkvB, 16384, 3072, 1024);

  // linear attention core
  attn_kv<<<dim3(64, 8), 256, 0, stream>>>(qkvB, kvg, ksumg);
  attn_out<<<dim3(64, 64), 256, 0, stream>>>(qkvB, kvg, ksumg, attn);

  // y = attn @ W_out : M=16384, N=1024, K=1024   (fp32 out -> d_out)
  gemm_bt<float><<<dim3(1024 / 128, 16384 / 128), 256, 0, stream>>>(attn, WoutT, out, 16384, 1024, 1024);
}

// Round 4
// 496.289 us; speedup vs baseline: 1.3129x; 1.3129x over previous
//
#include <hip/hip_runtime.h>
#include <hip/hip_bf16.h>

typedef __bf16 bf16;
typedef bf16 bf16x4 __attribute__((ext_vector_type(4)));
typedef bf16 bf16x8 __attribute__((ext_vector_type(8)));
typedef float f32x4 __attribute__((ext_vector_type(4)));

#define GLD_LDS16(gptr, lptr) \
  __builtin_amdgcn_global_load_lds((const __attribute__((address_space(1))) unsigned int*)(gptr), \
                                   (__attribute__((address_space(3))) unsigned int*)(lptr), 16, 0, 0)

// ---------------------------------------------------------------------------
// fp32 -> bf16 elementwise convert (8 elems/thread)
// ---------------------------------------------------------------------------
__global__ __launch_bounds__(256) void f32_to_bf16(const float* __restrict__ in,
                                                   bf16* __restrict__ out) {
  const size_t i = ((size_t)blockIdx.x * 256 + threadIdx.x) * 8;
  float4 a = *(const float4*)(in + i);
  float4 b = *(const float4*)(in + i + 4);
  bf16x8 o;
  o[0] = (bf16)a.x; o[1] = (bf16)a.y; o[2] = (bf16)a.z; o[3] = (bf16)a.w;
  o[4] = (bf16)b.x; o[5] = (bf16)b.y; o[6] = (bf16)b.z; o[7] = (bf16)b.w;
  *(bf16x8*)(out + i) = o;
}

// ---------------------------------------------------------------------------
// Transpose fp32 (R x C) -> bf16 (C x R), 32x32 LDS tiles
// ---------------------------------------------------------------------------
__global__ __launch_bounds__(256) void transpose_f32_bf16(const float* __restrict__ in,
                                                          bf16* __restrict__ out,
                                                          int R, int C) {
  __shared__ float tile[32][33];
  const int bx = blockIdx.x * 32;
  const int by = blockIdx.y * 32;
  const int tx = threadIdx.x & 31;
  const int ty = threadIdx.x >> 5;
#pragma unroll
  for (int i = 0; i < 4; i++) {
    int r = by + ty + i * 8;
    tile[ty + i * 8][tx] = in[(size_t)r * C + bx + tx];
  }
  __syncthreads();
#pragma unroll
  for (int i = 0; i < 4; i++) {
    int r = bx + ty + i * 8;
    out[(size_t)r * R + by + tx] = (bf16)tile[tx][ty + i * 8];
  }
}

// ---------------------------------------------------------------------------
// GEMM: C[M,N] = A[M,K] * BT[N,K]^T. bf16 in, OT out, fp32 MFMA accumulate.
// 128x128 tile, BK=64, global_load_lds width=16 async staging (m97 structure).
// ---------------------------------------------------------------------------
template <typename OT>
__global__ __launch_bounds__(256) void gemm_bt(const bf16* __restrict__ A,
                                               const bf16* __restrict__ BT,
                                               OT* __restrict__ C,
                                               int M, int N, int K) {
  __shared__ __attribute__((aligned(16))) bf16 As[128 * 64];
  __shared__ __attribute__((aligned(16))) bf16 Bs[128 * 64];
  const int tid = threadIdx.x;
  const int lane = tid & 63;
  const int wave = tid >> 6;
  const int wm = wave & 1, wn = wave >> 1;
  const int m0 = blockIdx.y * 128, n0 = blockIdx.x * 128;

  f32x4 acc[4][4];
#pragma unroll
  for (int i = 0; i < 4; i++)
#pragma unroll
    for (int j = 0; j < 4; j++) acc[i][j] = f32x4{0.f, 0.f, 0.f, 0.f};

  // staging: lane i of each wave deposits at wave-uniform base + i*16B.
  const int srow = lane >> 3;       // 0..7
  const int scol = (lane & 7) * 8;  // elems
  const int rbase = wave * 32;

  const bf16* Ag = A + (size_t)(m0 + rbase + srow) * K + scol;
  const bf16* Bg = BT + (size_t)(n0 + rbase + srow) * K + scol;
  bf16* Al = As + rbase * 64;
  bf16* Bl = Bs + rbase * 64;

  for (int k0 = 0; k0 < K; k0 += 64) {
#pragma unroll
    for (int i = 0; i < 4; i++) {
      GLD_LDS16(Ag + (size_t)i * 8 * K + k0, Al + i * 512);
      GLD_LDS16(Bg + (size_t)i * 8 * K + k0, Bl + i * 512);
    }
    __syncthreads();
    const int fr = lane & 15;
#pragma unroll
    for (int kk = 0; kk < 64; kk += 32) {
      const int kq = kk + ((lane >> 4) << 3);
      bf16x8 af[4], bfv[4];
#pragma unroll
      for (int mi = 0; mi < 4; mi++)
        af[mi] = *(const bf16x8*)(As + (wm * 64 + mi * 16 + fr) * 64 + kq);
#pragma unroll
      for (int ni = 0; ni < 4; ni++)
        bfv[ni] = *(const bf16x8*)(Bs + (wn * 64 + ni * 16 + fr) * 64 + kq);
#pragma unroll
      for (int mi = 0; mi < 4; mi++)
#pragma unroll
        for (int ni = 0; ni < 4; ni++)
          acc[mi][ni] = __builtin_amdgcn_mfma_f32_16x16x32_bf16(af[mi], bfv[ni], acc[mi][ni], 0, 0, 0);
    }
    __syncthreads();
  }

  const int col0 = n0 + wn * 64 + (lane & 15);
  const int row00 = m0 + wm * 64 + ((lane >> 4) << 2);
#pragma unroll
  for (int mi = 0; mi < 4; mi++)
#pragma unroll
    for (int ni = 0; ni < 4; ni++)
#pragma unroll
      for (int r = 0; r < 4; r++) {
        int row = row00 + mi * 16 + r;
        int col = col0 + ni * 16;
        C[(size_t)row * N + col] = (OT)acc[mi][ni][r];
      }
}

// ---------------------------------------------------------------------------
// attn_kv: per (b,h) kv[64][64] = sum_t kf[t] (x) v[t], ksum[64] = sum_t kf[t].
// grid (64 bh, 16 t-chunks of 256), 256 threads. 32-t phases, 2 barriers each.
// Thread (dq=tid&15, g=tid>>4) owns the 4x4 tile kv[dq*4+r][g*4+c].
// ---------------------------------------------------------------------------
__global__ __launch_bounds__(256) void attn_kv(const bf16* __restrict__ qkv,
                                               float* __restrict__ kvg,
                                               float* __restrict__ ksumg) {
  const int bh = blockIdx.x;
  const int b = bh >> 4, h = bh & 15;
  const int t0 = blockIdx.y * 256;
  __shared__ __attribute__((aligned(16))) float kf[32][68];
  __shared__ __attribute__((aligned(16))) float vf[32][68];
  const int tid = threadIdx.x;
  const int dq = tid & 15, g = tid >> 4;

  // per-thread rope constants (d = dp..dp+3 pairs with +32)
  const int tl = tid >> 3;         // 0..31 staged row
  const int dp = (tid & 7) * 4;    // 0..28
  float invf[4];
#pragma unroll
  for (int j = 0; j < 4; j++)
    invf[j] = (float)exp(-((double)(dp + j) / 32.0) * log(500000.0));

  f32x4 acc[4];  // acc[r][c] : rows dq*4+r, cols g*4+c
#pragma unroll
  for (int r = 0; r < 4; r++) acc[r] = f32x4{0.f, 0.f, 0.f, 0.f};
  float ksa[4] = {0.f, 0.f, 0.f, 0.f};

  for (int sc = 0; sc < 8; sc++) {
    const int tb = t0 + sc * 32;
    // load k pair halves + v straight to registers (no staging LDS)
    const bf16* base = qkv + (size_t)(b * 4096 + tb + tl) * 3072 + h * 64;
    bf16x4 klo = *(const bf16x4*)(base + 1024 + dp);
    bf16x4 khi = *(const bf16x4*)(base + 1024 + dp + 32);
    bf16x8 vv8 = *(const bf16x8*)(base + 2048 + (tid & 7) * 8);

    // rope + elu+1 in registers
    const float tf = (float)(tb + tl);
    f32x4 o1, o2;
#pragma unroll
    for (int j = 0; j < 4; j++) {
      float sn, cs;
      sincosf(tf * invf[j], &sn, &cs);
      float x1 = (float)klo[j], x2 = (float)khi[j];
      float r1 = x1 * cs - x2 * sn;
      float r2 = x2 * cs + x1 * sn;
      o1[j] = r1 > 0.f ? r1 + 1.f : __expf(r1);
      o2[j] = r2 > 0.f ? r2 + 1.f : __expf(r2);
    }
    *(f32x4*)&kf[tl][dp] = o1;
    *(f32x4*)&kf[tl][dp + 32] = o2;
    f32x4 va, vb;
#pragma unroll
    for (int j = 0; j < 4; j++) { va[j] = (float)vv8[j]; vb[j] = (float)vv8[j + 4]; }
    *(f32x4*)&vf[tl][(tid & 7) * 8] = va;
    *(f32x4*)&vf[tl][(tid & 7) * 8 + 4] = vb;
    __syncthreads();

    // accumulate 32 timesteps: 2x ds_read_b128 + 16 FMA per t
#pragma unroll 8
    for (int t = 0; t < 32; t++) {
      f32x4 kq = *(const f32x4*)&kf[t][dq * 4];
      f32x4 vq = *(const f32x4*)&vf[t][g * 4];
#pragma unroll
      for (int r = 0; r < 4; r++) {
#pragma unroll
        for (int c = 0; c < 4; c++) acc[r][c] += kq[r] * vq[c];
      }
      if (g == 0) {
#pragma unroll
        for (int r = 0; r < 4; r++) ksa[r] += kq[r];
      }
    }
    __syncthreads();
  }

#pragma unroll
  for (int r = 0; r < 4; r++)
#pragma unroll
    for (int c = 0; c < 4; c++)
      atomicAdd(&kvg[(size_t)bh * 4096 + (dq * 4 + r) * 64 + g * 4 + c], acc[r][c]);
  if (g == 0) {
#pragma unroll
    for (int r = 0; r < 4; r++) atomicAdd(&ksumg[bh * 64 + dq * 4 + r], ksa[r]);
  }
}

// ---------------------------------------------------------------------------
// attn_out: out[t] = (qf[t] @ kv) / max(qf[t]·ksum, 1e-6).
// grid (64 t-chunks, 64 bh), 256 threads. Vectorized staging + f32x4 kv reads.
// ---------------------------------------------------------------------------
__global__ __launch_bounds__(256) void attn_out(const bf16* __restrict__ qkv,
                                                const float* __restrict__ kvg,
                                                const float* __restrict__ ksumg,
                                                bf16* __restrict__ attn) {
  const int bh = blockIdx.y;
  const int b = bh >> 4, h = bh & 15;
  const int t0 = blockIdx.x * 64;
  __shared__ __attribute__((aligned(16))) float qf[64][68];
  __shared__ __attribute__((aligned(16))) float kvs[64][64];
  __shared__ __attribute__((aligned(16))) float ksums[64];
  const int tid = threadIdx.x;

  // stage q (bf16x8 loads -> fp32 LDS)
#pragma unroll
  for (int j = 0; j < 2; j++) {
    int chunk = tid + 256 * j;            // 0..511
    int tl = chunk >> 3, col = (chunk & 7) * 8;
    bf16x8 r = *(const bf16x8*)(qkv + (size_t)(b * 4096 + t0 + tl) * 3072 + h * 64 + col);
    f32x4 a, bb;
#pragma unroll
    for (int q = 0; q < 4; q++) { a[q] = (float)r[q]; bb[q] = (float)r[q + 4]; }
    *(f32x4*)&qf[tl][col] = a;
    *(f32x4*)&qf[tl][col + 4] = bb;
  }
  // stage kv (float4) + ksum
#pragma unroll
  for (int j = 0; j < 4; j++) {
    int idx = tid + 256 * j;              // 0..1023 float4 chunks
    *(float4*)&kvs[idx >> 4][(idx & 15) * 4] = *(const float4*)&kvg[(size_t)bh * 4096 + idx * 4];
  }
  if (tid < 64) ksums[tid] = ksumg[bh * 64 + tid];
  __syncthreads();

  // rope + scale + elu+1 in place
  {
    const int pd = tid & 31;
    const float invf = (float)exp(-((double)pd / 32.0) * log(500000.0));
#pragma unroll
    for (int j = 0; j < 8; j++) {
      int idx = tid + 256 * j;
      int tl = idx >> 5;
      int d = idx & 31;
      float x1 = qf[tl][d], x2 = qf[tl][d + 32];
      float sn, cs;
      sincosf((float)(t0 + tl) * invf, &sn, &cs);
      float r1 = (x1 * cs - x2 * sn) * 0.125f;
      float r2 = (x2 * cs + x1 * sn) * 0.125f;
      qf[tl][d] = r1 > 0.f ? r1 + 1.f : __expf(r1);
      qf[tl][d + 32] = r2 > 0.f ? r2 + 1.f : __expf(r2);
    }
  }
  __syncthreads();

  const int tl = tid >> 2, s = tid & 3;
  float dn = 0.f;
#pragma unroll
  for (int dd = 0; dd < 16; dd++) {
    f32x4 qv4 = *(const f32x4*)&qf[tl][dd * 4];
    f32x4 ks4 = *(const f32x4*)&ksums[dd * 4];
    dn += qv4[0] * ks4[0] + qv4[1] * ks4[1] + qv4[2] * ks4[2] + qv4[3] * ks4[3];
  }
  dn = fmaxf(dn, 1e-6f);
  const float rdn = 1.f / dn;

  f32x4 acc4[4];
#pragma unroll
  for (int q = 0; q < 4; q++) acc4[q] = f32x4{0.f, 0.f, 0.f, 0.f};
  for (int d2 = 0; d2 < 64; d2++) {
    float qv = qf[tl][d2];
#pragma unroll
    for (int q = 0; q < 4; q++) {
      f32x4 kq = *(const f32x4*)&kvs[d2][s * 16 + q * 4];
#pragma unroll
      for (int c = 0; c < 4; c++) acc4[q][c] += qv * kq[c];
    }
  }

  union {
    __bf16 hh[16];
    uint4 qq[2];
  } ob;
#pragma unroll
  for (int q = 0; q < 4; q++)
#pragma unroll
    for (int c = 0; c < 4; c++) ob.hh[q * 4 + c] = (__bf16)(acc4[q][c] * rdn);
  bf16* dst = attn + (size_t)(b * 4096 + t0 + tl) * 1024 + h * 64 + s * 16;
  *reinterpret_cast<uint4*>(dst) = ob.qq[0];
  *reinterpret_cast<uint4*>(dst + 8) = ob.qq[1];
}

// ---------------------------------------------------------------------------
// Workspace layout (bytes):
//   kvg   f32  [64*64*64]   @ 0          size   1048576
//   ksumg f32  [64*64]      @ 1048576    size     16384
//   WqkvT bf16 [3072,1024]  @ 1064960    size   6291456
//   WoutT bf16 [1024,1024]  @ 7356416    size   2097152
//   attn  bf16 [16384,1024] @ 9453568    size  33554432
//   qkvB  bf16 [16384,3072] @ 43008000   size 100663296
//   xB    bf16 [16384,1024] @ 143671296  size  33554432
//   total 177225728 (~169 MiB)
// ---------------------------------------------------------------------------
extern "C" void kernel_launch(void* const* d_in, const int* in_sizes, int n_in,
                              void* d_out, int out_size, void* d_ws, size_t ws_size,
                              hipStream_t stream) {
  if (ws_size < 177225728ULL) return;

  const float* x = (const float*)d_in[0];
  const float* Wqkv = (const float*)d_in[1];
  const float* Wout = (const float*)d_in[2];
  float* out = (float*)d_out;
  char* ws = (char*)d_ws;

  float* kvg = (float*)(ws);
  float* ksumg = (float*)(ws + 1048576);
  bf16* WqkvT = (bf16*)(ws + 1064960);
  bf16* WoutT = (bf16*)(ws + 7356416);
  bf16* attn = (bf16*)(ws + 9453568);
  bf16* qkvB = (bf16*)(ws + 43008000);
  bf16* xB = (bf16*)(ws + 143671296);

  hipMemsetAsync(ws, 0, 1048576 + 16384, stream);

  f32_to_bf16<<<16777216 / (256 * 8), 256, 0, stream>>>(x, xB);
  transpose_f32_bf16<<<dim3(3072 / 32, 1024 / 32), 256, 0, stream>>>(Wqkv, WqkvT, 1024, 3072);
  transpose_f32_bf16<<<dim3(1024 / 32, 1024 / 32), 256, 0, stream>>>(Wout, WoutT, 1024, 1024);

  gemm_bt<bf16><<<dim3(3072 / 128, 16384 / 128), 256, 0, stream>>>(xB, WqkvT, qkvB, 16384, 3072, 1024);

  attn_kv<<<dim3(64, 16), 256, 0, stream>>>(qkvB, kvg, ksumg);
  attn_out<<<dim3(64, 64), 256, 0, stream>>>(qkvB, kvg, ksumg, attn);

  gemm_bt<float><<<dim3(1024 / 128, 16384 / 128), 256, 0, stream>>>(attn, WoutT, out, 16384, 1024, 1024);
}

// Round 5
// 425.853 us; speedup vs baseline: 1.5301x; 1.1654x over previous
//
#include <hip/hip_runtime.h>
#include <hip/hip_bf16.h>

typedef __bf16 bf16;
typedef bf16 bf16x4 __attribute__((ext_vector_type(4)));
typedef bf16 bf16x8 __attribute__((ext_vector_type(8)));
typedef float f32x4 __attribute__((ext_vector_type(4)));

#define GLD_LDS16(gptr, lptr) \
  __builtin_amdgcn_global_load_lds((const __attribute__((address_space(1))) unsigned int*)(gptr), \
                                   (__attribute__((address_space(3))) unsigned int*)(lptr), 16, 0, 0)

// ---------------------------------------------------------------------------
// fp32 -> bf16 elementwise convert (8 elems/thread)
// ---------------------------------------------------------------------------
__global__ __launch_bounds__(256) void f32_to_bf16(const float* __restrict__ in,
                                                   bf16* __restrict__ out) {
  const size_t i = ((size_t)blockIdx.x * 256 + threadIdx.x) * 8;
  float4 a = *(const float4*)(in + i);
  float4 b = *(const float4*)(in + i + 4);
  bf16x8 o;
  o[0] = (bf16)a.x; o[1] = (bf16)a.y; o[2] = (bf16)a.z; o[3] = (bf16)a.w;
  o[4] = (bf16)b.x; o[5] = (bf16)b.y; o[6] = (bf16)b.z; o[7] = (bf16)b.w;
  *(bf16x8*)(out + i) = o;
}

// ---------------------------------------------------------------------------
// Transpose fp32 (R x C) -> bf16 (C x R), 32x32 LDS tiles
// ---------------------------------------------------------------------------
__global__ __launch_bounds__(256) void transpose_f32_bf16(const float* __restrict__ in,
                                                          bf16* __restrict__ out,
                                                          int R, int C) {
  __shared__ float tile[32][33];
  const int bx = blockIdx.x * 32;
  const int by = blockIdx.y * 32;
  const int tx = threadIdx.x & 31;
  const int ty = threadIdx.x >> 5;
#pragma unroll
  for (int i = 0; i < 4; i++) {
    int r = by + ty + i * 8;
    tile[ty + i * 8][tx] = in[(size_t)r * C + bx + tx];
  }
  __syncthreads();
#pragma unroll
  for (int i = 0; i < 4; i++) {
    int r = bx + ty + i * 8;
    out[(size_t)r * R + by + tx] = (bf16)tile[tx][ty + i * 8];
  }
}

// ---------------------------------------------------------------------------
// Shared GEMM core: 128x128 tile, BK=64, global_load_lds width=16, XOR-swizzled
// LDS (phys chunk = logical chunk ^ (row&7)) to kill bank conflicts on the
// ds_read_b128 fragment loads (row stride 128B == 32 banks otherwise).
// Computes acc[4][4] (f32x4 each) for this thread; caller does the epilogue.
// ---------------------------------------------------------------------------
__device__ __forceinline__ void gemm_core(const bf16* __restrict__ A,
                                          const bf16* __restrict__ BT,
                                          int K, int m0, int n0,
                                          bf16* As, bf16* Bs,
                                          f32x4 acc[4][4]) {
  const int tid = threadIdx.x;
  const int lane = tid & 63;
  const int wave = tid >> 6;
  const int wm = wave & 1, wn = wave >> 1;

#pragma unroll
  for (int i = 0; i < 4; i++)
#pragma unroll
    for (int j = 0; j < 4; j++) acc[i][j] = f32x4{0.f, 0.f, 0.f, 0.f};

  // staging: lane deposits at wave-base + lane*16B == (row rbase+srow, chunk pch).
  // Source column is swizzled so that phys chunk p holds logical chunk p^(row&7).
  const int srow = lane >> 3;              // 0..7
  const int pch = lane & 7;                // physical chunk
  const int scol = (pch ^ srow) * 8;       // swizzled logical column (elems)
  const int rbase = wave * 32;

  const bf16* Ag = A + (size_t)(m0 + rbase + srow) * K + scol;
  const bf16* Bg = BT + (size_t)(n0 + rbase + srow) * K + scol;
  bf16* Al = As + rbase * 64;
  bf16* Bl = Bs + rbase * 64;

  for (int k0 = 0; k0 < K; k0 += 64) {
#pragma unroll
    for (int i = 0; i < 4; i++) {
      GLD_LDS16(Ag + (size_t)i * 8 * K + k0, Al + i * 512);
      GLD_LDS16(Bg + (size_t)i * 8 * K + k0, Bl + i * 512);
    }
    __syncthreads();
    const int fr = lane & 15;
    const int sw = fr & 7;
#pragma unroll
    for (int kk = 0; kk < 64; kk += 32) {
      const int lc = (kk >> 3) + (lane >> 4);  // logical chunk 0..7
      const int pc8 = (lc ^ sw) * 8;           // phys chunk offset (elems)
      bf16x8 af[4], bfv[4];
#pragma unroll
      for (int mi = 0; mi < 4; mi++)
        af[mi] = *(const bf16x8*)(As + (wm * 64 + mi * 16 + fr) * 64 + pc8);
#pragma unroll
      for (int ni = 0; ni < 4; ni++)
        bfv[ni] = *(const bf16x8*)(Bs + (wn * 64 + ni * 16 + fr) * 64 + pc8);
#pragma unroll
      for (int mi = 0; mi < 4; mi++)
#pragma unroll
        for (int ni = 0; ni < 4; ni++)
          acc[mi][ni] = __builtin_amdgcn_mfma_f32_16x16x32_bf16(af[mi], bfv[ni], acc[mi][ni], 0, 0, 0);
    }
    __syncthreads();
  }
}

// ---------------------------------------------------------------------------
// QKV GEMM with fused rope+scale+elu+1 epilogue.
// Input x[16384,1024] bf16, WqkvT[3072,1024] bf16.
// Output head-major bf16: qf/kf/vf [bh=64][t=4096][d=64].
// A wave's 64-col span == exactly one head; lane holds both rope halves
// (ni and ni+2) of each row -> rope is lane-local on the fp32 accumulator.
// ---------------------------------------------------------------------------
__global__ __launch_bounds__(256) void gemm_qkv_fused(const bf16* __restrict__ A,
                                                      const bf16* __restrict__ BT,
                                                      bf16* __restrict__ qfB,
                                                      bf16* __restrict__ kfB,
                                                      bf16* __restrict__ vfB) {
  __shared__ __attribute__((aligned(16))) bf16 As[128 * 64];
  __shared__ __attribute__((aligned(16))) bf16 Bs[128 * 64];
  const int K = 1024;
  const int m0 = blockIdx.y * 128, n0 = blockIdx.x * 128;

  f32x4 acc[4][4];
  gemm_core(A, BT, K, m0, n0, As, Bs, acc);

  const int lane = threadIdx.x & 63;
  const int wave = threadIdx.x >> 6;
  const int wm = wave & 1, wn = wave >> 1;
  const int cb = n0 + wn * 64;            // wave-uniform column block (one head)
  const int p = cb >> 10;                 // 0=q, 1=k, 2=v
  const int hh = (cb & 1023) >> 6;
  const int fr15 = lane & 15;
  const int row00 = m0 + wm * 64 + ((lane >> 4) << 2);
  const int b = row00 >> 12;              // wave-uniform (blocks never straddle batch)
  const size_t base0 = ((size_t)(b * 16 + hh)) * 4096 * 64;

  if (p == 2) {
#pragma unroll
    for (int mi = 0; mi < 4; mi++)
#pragma unroll
      for (int r = 0; r < 4; r++) {
        const int tloc = (row00 + mi * 16 + r) & 4095;
        bf16* dst = vfB + base0 + (size_t)tloc * 64;
#pragma unroll
        for (int ni = 0; ni < 4; ni++) dst[fr15 + ni * 16] = (bf16)acc[mi][ni][r];
      }
  } else {
    bf16* outp = (p == 0) ? qfB : kfB;
    const float scl = (p == 0) ? 0.125f : 1.0f;
    const float invf0 = (float)exp(-((double)fr15 / 32.0) * log(500000.0));
    const float invf1 = (float)exp(-((double)(fr15 + 16) / 32.0) * log(500000.0));
#pragma unroll
    for (int mi = 0; mi < 4; mi++)
#pragma unroll
      for (int r = 0; r < 4; r++) {
        const int tloc = (row00 + mi * 16 + r) & 4095;
        const float tf = (float)tloc;
        bf16* dst = outp + base0 + (size_t)tloc * 64;
#pragma unroll
        for (int ni = 0; ni < 2; ni++) {
          float x1 = acc[mi][ni][r], x2 = acc[mi][ni + 2][r];
          float sn, cs;
          sincosf(tf * (ni ? invf1 : invf0), &sn, &cs);
          float r1 = (x1 * cs - x2 * sn) * scl;
          float r2 = (x2 * cs + x1 * sn) * scl;
          dst[fr15 + ni * 16] = (bf16)(r1 > 0.f ? r1 + 1.f : __expf(r1));
          dst[fr15 + ni * 16 + 32] = (bf16)(r2 > 0.f ? r2 + 1.f : __expf(r2));
        }
      }
  }
}

// ---------------------------------------------------------------------------
// Plain GEMM (final projection): C fp32 = A bf16 @ BT^T bf16.
// ---------------------------------------------------------------------------
__global__ __launch_bounds__(256) void gemm_bt_f32(const bf16* __restrict__ A,
                                                   const bf16* __restrict__ BT,
                                                   float* __restrict__ C,
                                                   int N, int K) {
  __shared__ __attribute__((aligned(16))) bf16 As[128 * 64];
  __shared__ __attribute__((aligned(16))) bf16 Bs[128 * 64];
  const int m0 = blockIdx.y * 128, n0 = blockIdx.x * 128;

  f32x4 acc[4][4];
  gemm_core(A, BT, K, m0, n0, As, Bs, acc);

  const int lane = threadIdx.x & 63;
  const int wave = threadIdx.x >> 6;
  const int wm = wave & 1, wn = wave >> 1;
  const int col0 = n0 + wn * 64 + (lane & 15);
  const int row00 = m0 + wm * 64 + ((lane >> 4) << 2);
#pragma unroll
  for (int mi = 0; mi < 4; mi++)
#pragma unroll
    for (int ni = 0; ni < 4; ni++)
#pragma unroll
      for (int r = 0; r < 4; r++)
        C[(size_t)(row00 + mi * 16 + r) * N + col0 + ni * 16] = acc[mi][ni][r];
}

// ---------------------------------------------------------------------------
// attn_kv: per (b,h) kv[64][64] = sum_t kf[t] (x) v[t], ksum[64] = sum_t kf[t].
// Inputs head-major bf16 (already roped+elu'd). grid (64 bh, 16 t-chunks).
// Thread (dq=tid&15, g=tid>>4) owns 4x4 tile kv[dq*4+r][g*4+c].
// ---------------------------------------------------------------------------
__global__ __launch_bounds__(256) void attn_kv(const bf16* __restrict__ kfB,
                                               const bf16* __restrict__ vfB,
                                               float* __restrict__ kvg,
                                               float* __restrict__ ksumg) {
  const int bh = blockIdx.x;
  const int t0 = blockIdx.y * 256;
  __shared__ __attribute__((aligned(16))) float kfs[32][68];
  __shared__ __attribute__((aligned(16))) float vfs[32][68];
  const int tid = threadIdx.x;
  const int dq = tid & 15, g = tid >> 4;
  const int tl = tid >> 3, ch = (tid & 7) * 8;

  f32x4 acc[4];
#pragma unroll
  for (int r = 0; r < 4; r++) acc[r] = f32x4{0.f, 0.f, 0.f, 0.f};
  float ksa[4] = {0.f, 0.f, 0.f, 0.f};

  for (int sc = 0; sc < 8; sc++) {
    const size_t rowb = ((size_t)bh * 4096 + t0 + sc * 32 + tl) * 64 + ch;
    bf16x8 k8 = *(const bf16x8*)(kfB + rowb);
    bf16x8 v8 = *(const bf16x8*)(vfB + rowb);
    f32x4 ka, kb, va, vb;
#pragma unroll
    for (int j = 0; j < 4; j++) {
      ka[j] = (float)k8[j]; kb[j] = (float)k8[j + 4];
      va[j] = (float)v8[j]; vb[j] = (float)v8[j + 4];
    }
    *(f32x4*)&kfs[tl][ch] = ka;
    *(f32x4*)&kfs[tl][ch + 4] = kb;
    *(f32x4*)&vfs[tl][ch] = va;
    *(f32x4*)&vfs[tl][ch + 4] = vb;
    __syncthreads();

#pragma unroll 8
    for (int t = 0; t < 32; t++) {
      f32x4 kq = *(const f32x4*)&kfs[t][dq * 4];
      f32x4 vq = *(const f32x4*)&vfs[t][g * 4];
#pragma unroll
      for (int r = 0; r < 4; r++) {
#pragma unroll
        for (int c = 0; c < 4; c++) acc[r][c] += kq[r] * vq[c];
      }
      if (g == 0) {
#pragma unroll
        for (int r = 0; r < 4; r++) ksa[r] += kq[r];
      }
    }
    __syncthreads();
  }

#pragma unroll
  for (int r = 0; r < 4; r++)
#pragma unroll
    for (int c = 0; c < 4; c++)
      atomicAdd(&kvg[(size_t)bh * 4096 + (dq * 4 + r) * 64 + g * 4 + c], acc[r][c]);
  if (g == 0) {
#pragma unroll
    for (int r = 0; r < 4; r++) atomicAdd(&ksumg[bh * 64 + dq * 4 + r], ksa[r]);
  }
}

// ---------------------------------------------------------------------------
// attn_out: out[t] = (qf[t] @ kv) / max(qf[t]·ksum, 1e-6).
// grid (64 t-chunks, 64 bh). Thread (tr=tid>>4, cc=tid&15) -> 4 rows x 4 cols.
// Quarter-wave has tr uniform -> qf reads broadcast; kv reads 2-way (free).
// Writes attn in d_model layout [b*4096+t][h*64+d] for the final GEMM.
// ---------------------------------------------------------------------------
__global__ __launch_bounds__(256) void attn_out(const bf16* __restrict__ qfB,
                                                const float* __restrict__ kvg,
                                                const float* __restrict__ ksumg,
                                                bf16* __restrict__ attn) {
  const int bh = blockIdx.y;
  const int b = bh >> 4, h = bh & 15;
  const int t0 = blockIdx.x * 64;
  __shared__ __attribute__((aligned(16))) float qf[64][68];
  __shared__ __attribute__((aligned(16))) float kvs[64][64];
  __shared__ __attribute__((aligned(16))) float ksums[64];
  const int tid = threadIdx.x;

  // stage qf (contiguous bf16x8 -> fp32 LDS)
#pragma unroll
  for (int j = 0; j < 2; j++) {
    int chunk = tid + 256 * j;           // 0..511
    int tl = chunk >> 3, col = (chunk & 7) * 8;
    bf16x8 r = *(const bf16x8*)(qfB + ((size_t)bh * 4096 + t0 + tl) * 64 + col);
    f32x4 a, bb;
#pragma unroll
    for (int q = 0; q < 4; q++) { a[q] = (float)r[q]; bb[q] = (float)r[q + 4]; }
    *(f32x4*)&qf[tl][col] = a;
    *(f32x4*)&qf[tl][col + 4] = bb;
  }
  // stage kv (float4) + ksum
#pragma unroll
  for (int j = 0; j < 4; j++) {
    int idx = tid + 256 * j;             // 0..1023 float4 chunks
    *(float4*)&kvs[idx >> 4][(idx & 15) * 4] = *(const float4*)&kvg[(size_t)bh * 4096 + idx * 4];
  }
  if (tid < 64) ksums[tid] = ksumg[bh * 64 + tid];
  __syncthreads();

  const int tr = tid >> 4, cc = tid & 15;
  f32x4 acc[4];
#pragma unroll
  for (int r = 0; r < 4; r++) acc[r] = f32x4{0.f, 0.f, 0.f, 0.f};
  f32x4 dn = f32x4{0.f, 0.f, 0.f, 0.f};

  for (int d2 = 0; d2 < 64; d2++) {
    f32x4 kv4 = *(const f32x4*)&kvs[d2][cc * 4];
    float ks = ksums[d2];
#pragma unroll
    for (int r = 0; r < 4; r++) {
      float qv = qf[tr * 4 + r][d2];     // broadcast within quarter-wave
      acc[r] += qv * kv4;
      dn[r] += qv * ks;
    }
  }

#pragma unroll
  for (int r = 0; r < 4; r++) {
    const float rdn = 1.f / fmaxf(dn[r], 1e-6f);
    bf16x4 o;
#pragma unroll
    for (int c = 0; c < 4; c++) o[c] = (bf16)(acc[r][c] * rdn);
    *(bf16x4*)(attn + ((size_t)(b * 4096) + t0 + tr * 4 + r) * 1024 + h * 64 + cc * 4) = o;
  }
}

// ---------------------------------------------------------------------------
// Workspace layout (bytes):
//   kvg   f32  [64*64*64]     @ 0          size   1048576
//   ksumg f32  [64*64]        @ 1048576    size     16384
//   WqkvT bf16 [3072,1024]    @ 1064960    size   6291456
//   WoutT bf16 [1024,1024]    @ 7356416    size   2097152
//   attn  bf16 [16384,1024]   @ 9453568    size  33554432
//   qfB   bf16 [64,4096,64]   @ 43008000   size  33554432
//   kfB   bf16 [64,4096,64]   @ 76562432   size  33554432
//   vfB   bf16 [64,4096,64]   @ 110116864  size  33554432
//   xB    bf16 [16384,1024]   @ 143671296  size  33554432
//   total 177225728 (~169 MiB)
// ---------------------------------------------------------------------------
extern "C" void kernel_launch(void* const* d_in, const int* in_sizes, int n_in,
                              void* d_out, int out_size, void* d_ws, size_t ws_size,
                              hipStream_t stream) {
  if (ws_size < 177225728ULL) return;

  const float* x = (const float*)d_in[0];
  const float* Wqkv = (const float*)d_in[1];
  const float* Wout = (const float*)d_in[2];
  float* out = (float*)d_out;
  char* ws = (char*)d_ws;

  float* kvg = (float*)(ws);
  float* ksumg = (float*)(ws + 1048576);
  bf16* WqkvT = (bf16*)(ws + 1064960);
  bf16* WoutT = (bf16*)(ws + 7356416);
  bf16* attn = (bf16*)(ws + 9453568);
  bf16* qfB = (bf16*)(ws + 43008000);
  bf16* kfB = (bf16*)(ws + 76562432);
  bf16* vfB = (bf16*)(ws + 110116864);
  bf16* xB = (bf16*)(ws + 143671296);

  hipMemsetAsync(ws, 0, 1048576 + 16384, stream);

  f32_to_bf16<<<16777216 / (256 * 8), 256, 0, stream>>>(x, xB);
  transpose_f32_bf16<<<dim3(3072 / 32, 1024 / 32), 256, 0, stream>>>(Wqkv, WqkvT, 1024, 3072);
  transpose_f32_bf16<<<dim3(1024 / 32, 1024 / 32), 256, 0, stream>>>(Wout, WoutT, 1024, 1024);

  // qkv = x @ W_qkv with fused rope/scale/elu+1 -> head-major qf/kf/vf
  gemm_qkv_fused<<<dim3(3072 / 128, 16384 / 128), 256, 0, stream>>>(xB, WqkvT, qfB, kfB, vfB);

  // linear attention core
  attn_kv<<<dim3(64, 16), 256, 0, stream>>>(kfB, vfB, kvg, ksumg);
  attn_out<<<dim3(64, 64), 256, 0, stream>>>(qfB, kvg, ksumg, attn);

  // y = attn @ W_out -> fp32 d_out
  gemm_bt_f32<<<dim3(1024 / 128, 16384 / 128), 256, 0, stream>>>(attn, WoutT, out, 1024, 1024);
}